// Round 9
// baseline (401.117 us; speedup 1.0000x reference)
//
#include <hip/hip_runtime.h>

#define DN  256   // DAGs
#define NN  1024  // nodes per DAG
#define PP  8     // max predecessors
#define LL  104   // feature dim
#define CLS 500   // classes
#define BT  512   // threads per block (8 waves)
#define TMAX 64   // node tile per level pass
#define KP  232   // padded K stride in bf16 elems (116 dwords % 32 = 20 -> 2-way max, free)
#define NG  26    // float4 feature groups (104/4)

typedef __attribute__((ext_vector_type(8))) short short8;
typedef __attribute__((ext_vector_type(4))) short short4v;
typedef __attribute__((ext_vector_type(4))) float f32x4;

#define MFMA(a, b, c) __builtin_amdgcn_mfma_f32_16x16x32_bf16((a), (b), (c), 0, 0, 0)

__device__ __forceinline__ void split_bf16(float x, unsigned short& h, unsigned short& l) {
    unsigned u = __float_as_uint(x);
    h = (unsigned short)(u >> 16);
    float hf = __uint_as_float(u & 0xFFFF0000u);
    l = (unsigned short)(__float_as_uint(x - hf) >> 16);
}

// One block per DAG, 8 waves. Level-scheduled; per-level matvec batch is a
// split-bf16 MFMA GEMM. Wave w (<7) owns ONE 16-col nt-tile of W (56 regs, no
// duplication); freed registers fund a 2-deep software pipeline in phase A
// (ping-pong load sets A/B) so gather latency overlaps softmax compute.
__global__ __launch_bounds__(BT, 2) void dag_level_kernel(
    const float* __restrict__ atom,      // [DN][NN][LL]
    const int*   __restrict__ pred,      // [DN][NN][PP]
    const float* __restrict__ W_single,  // [LL][LL]
    const float* __restrict__ b_single,  // [LL]
    const float* __restrict__ W_merge,   // [LL][2*LL]
    const float* __restrict__ b_merge,   // [LL]
    const float* __restrict__ attn_w,    // [LL]
    float* __restrict__ out_all,         // ws: [DN][NN][LL]
    float* __restrict__ last_buf)        // ws: [DN][LL]
{
    __shared__ __align__(16) unsigned short x_hi[TMAX][KP];  // 29.7 KB
    __shared__ __align__(16) unsigned short x_lo[TMAX][KP];  // 29.7 KB
    __shared__ int   lvl[NN];               // 4 KB
    __shared__ int   cnt[NN];               // 4 KB
    __shared__ unsigned short order[NN];    // 2 KB
    __shared__ __align__(16) float s_attn2[LL];   // attn_w * log2(e)
    __shared__ float s_bm[LL];
    __shared__ int   csum[64];
    __shared__ int   s_flag, s_maxlvl;

    const int d    = blockIdx.x;
    const int tid  = threadIdx.x;
    const int wid  = tid >> 6;
    const int lane = tid & 63;

    const float* atom_d = atom + (size_t)d * NN * LL;
    const int*   pred_d = pred + (size_t)d * NN * PP;
    float*       out_d  = out_all + (size_t)d * NN * LL;

    // ---- W_merge fragments -> registers. Wave w owns nt = min(w,6):
    // lane holds W[col = nt*16 + (lane&15)][k = kt*32 + (lane>>4)*8 + j].
    short8 wh[7], wl[7];
    {
        const int r = min(wid, 6)*16 + (lane & 15);
        #pragma unroll
        for (int kt = 0; kt < 7; ++kt) {
            const int k0 = kt*32 + (lane >> 4)*8;
            short8 hh, lo8;
            #pragma unroll
            for (int j = 0; j < 8; ++j) {
                float v = (r < LL && (k0 + j) < 2*LL) ? W_merge[r*2*LL + k0 + j] : 0.f;
                unsigned short a, b;
                split_bf16(v, a, b);
                hh[j] = (short)a; lo8[j] = (short)b;
            }
            wh[kt] = hh; wl[kt] = lo8;
        }
    }

    // ---- init: zero x pad cols, stage attn/bias, init flags ----
    for (int idx = tid; idx < TMAX * (KP - 2*LL); idx += BT) {
        int rr = idx / (KP - 2*LL), cc = 2*LL + (idx - rr*(KP - 2*LL));
        x_hi[rr][cc] = 0; x_lo[rr][cc] = 0;
    }
    if (tid < LL) { s_attn2[tid] = attn_w[tid] * 1.44269504f; s_bm[tid] = b_merge[tid]; }
    if (tid == 0) { s_flag = 0; s_maxlvl = 0; }

    // ---- 1. level relaxation (2 nodes per thread, preds in registers) ----
    {
        int mypA[PP], mypB[PP];
        const int4* p4 = (const int4*)(pred_d + tid * PP);
        int4 a = p4[0], b = p4[1];
        mypA[0]=a.x; mypA[1]=a.y; mypA[2]=a.z; mypA[3]=a.w;
        mypA[4]=b.x; mypA[5]=b.y; mypA[6]=b.z; mypA[7]=b.w;
        const int4* q4 = (const int4*)(pred_d + (tid + BT) * PP);
        int4 c = q4[0], e = q4[1];
        mypB[0]=c.x; mypB[1]=c.y; mypB[2]=c.z; mypB[3]=c.w;
        mypB[4]=e.x; mypB[5]=e.y; mypB[6]=e.z; mypB[7]=e.w;
        lvl[tid] = 0; lvl[tid + BT] = 0;
        __syncthreads();
        for (int it = 1; it <= NN; ++it) {
            int mxA = -1, mxB = -1;
            #pragma unroll
            for (int q = 0; q < PP; ++q) {
                if (mypA[q] >= 0) mxA = max(mxA, lvl[mypA[q]]);
                if (mypB[q] >= 0) mxB = max(mxB, lvl[mypB[q]]);
            }
            bool ch = false;
            if (mxA + 1 != lvl[tid])      { lvl[tid]      = mxA + 1; ch = true; }
            if (mxB + 1 != lvl[tid + BT]) { lvl[tid + BT] = mxB + 1; ch = true; }
            if (ch) s_flag = it;
            __syncthreads();
            int f = s_flag;
            __syncthreads();
            if (f != it) break;
        }
        atomicMax(&s_maxlvl, max(lvl[tid], lvl[tid + BT]));
    }

    // ---- 2. counting sort by level ----
    cnt[tid] = 0; cnt[tid + BT] = 0;
    __syncthreads();
    atomicAdd(&cnt[lvl[tid]], 1);
    atomicAdd(&cnt[lvl[tid + BT]], 1);
    __syncthreads();
    if (tid < 64) { int s = 0; for (int i = 0; i < 16; ++i) s += cnt[tid*16 + i]; csum[tid] = s; }
    __syncthreads();
    if (tid == 0) { int run = 0; for (int t = 0; t < 64; ++t) { int c = csum[t]; csum[t] = run; run += c; } }
    __syncthreads();
    if (tid < 64) {
        int run = csum[tid];
        for (int i = 0; i < 16; ++i) { int c = cnt[tid*16 + i]; cnt[tid*16 + i] = run; run += c; }
    }
    __syncthreads();
    {
        int pos = atomicAdd(&cnt[lvl[tid]], 1);      order[pos] = (unsigned short)tid;
        pos     = atomicAdd(&cnt[lvl[tid + BT]], 1); order[pos] = (unsigned short)(tid + BT);
    }
    __syncthreads();
    // level L occupies [L==0 ? 0 : cnt[L-1], cnt[L])

    // ---- 3. level-0 (root) nodes via W_single straight from global ----
    {
        int nroots = cnt[0];
        for (int task = tid; task < nroots * LL; task += BT) {
            int ni = task / LL, r = task - ni * LL;
            int n = order[ni];
            float acc = b_single[r];
            const float* feat = atom_d + n * LL;
            const float* wr = W_single + r * LL;
            #pragma unroll 8
            for (int l = 0; l < LL; ++l) acc = fmaf(wr[l], feat[l], acc);
            float v = fmaxf(acc, 0.f);
            out_d[n * LL + r] = v;
            if (n == NN - 1) last_buf[d * LL + r] = v;
        }
    }
    __syncthreads();

    // ---- phase A helpers: explicit ping-pong register sets (static names) ----
#define DECLP(S) int pi##S[PP]; float4 po##S[PP]; float4 ft##S; int ni##S, lg##S;

#define LOADP(S, TASK)                                                          \
    {                                                                           \
        int tt_ = min((TASK), ntask - 1);                                       \
        ni##S = tt_ / NG; lg##S = tt_ - ni##S * NG;                             \
        int n_ = order[t0 + ni##S];                                             \
        const int4* pp4_ = (const int4*)(pred_d + n_ * PP);                     \
        int4 pa_ = pp4_[0], pb_ = pp4_[1];                                      \
        pi##S[0]=pa_.x; pi##S[1]=pa_.y; pi##S[2]=pa_.z; pi##S[3]=pa_.w;         \
        pi##S[4]=pb_.x; pi##S[5]=pb_.y; pi##S[6]=pb_.z; pi##S[7]=pb_.w;         \
        ft##S = *(const float4*)&atom_d[n_ * LL + lg##S * 4];                   \
        _Pragma("unroll")                                                       \
        for (int q_ = 0; q_ < PP; ++q_) {                                       \
            int idx_ = max(pi##S[q_], 0);                                       \
            po##S[q_] = *(const float4*)&out_d[idx_ * LL + lg##S * 4];          \
        }                                                                       \
    }

#define COMPP(S)                                                                \
    {                                                                           \
        float4 aw_ = *(const float4*)&s_attn2[lg##S * 4];                       \
        float awv_[4] = {aw_.x, aw_.y, aw_.z, aw_.w};                           \
        float ftv_[4] = {ft##S.x, ft##S.y, ft##S.z, ft##S.w};                   \
        unsigned short oh_[8], ol_[8];                                          \
        _Pragma("unroll")                                                       \
        for (int f_ = 0; f_ < 4; ++f_) {                                        \
            float den_ = 0.f, num_ = 0.f;                                       \
            _Pragma("unroll")                                                   \
            for (int q_ = 0; q_ < PP; ++q_) {                                   \
                float pv_ = ((const float*)&po##S[q_])[f_];                     \
                float e_ = exp2f(awv_[f_] * pv_);                               \
                e_ = (pi##S[q_] >= 0) ? e_ : 0.f;                               \
                den_ += e_;                                                     \
                num_ = fmaf(e_, pv_, num_);                                     \
            }                                                                   \
            float agg_ = __fdividef(num_, den_);                                \
            split_bf16(agg_,      oh_[f_],     ol_[f_]);                        \
            split_bf16(ftv_[f_],  oh_[4+f_],   ol_[4+f_]);                      \
        }                                                                       \
        short4v h0_ = {(short)oh_[0], (short)oh_[1], (short)oh_[2], (short)oh_[3]}; \
        short4v l0_ = {(short)ol_[0], (short)ol_[1], (short)ol_[2], (short)ol_[3]}; \
        short4v h1_ = {(short)oh_[4], (short)oh_[5], (short)oh_[6], (short)oh_[7]}; \
        short4v l1_ = {(short)ol_[4], (short)ol_[5], (short)ol_[6], (short)ol_[7]}; \
        *(short4v*)&x_hi[ni##S][lg##S*4]      = h0_;                            \
        *(short4v*)&x_lo[ni##S][lg##S*4]      = l0_;                            \
        *(short4v*)&x_hi[ni##S][LL + lg##S*4] = h1_;                            \
        *(short4v*)&x_lo[ni##S][LL + lg##S*4] = l1_;                            \
    }

    // ---- 4. main level loop ----
    const int maxlvl = s_maxlvl;
    for (int L = 1; L <= maxlvl; ++L) {
        const int s = cnt[L - 1], e = cnt[L];
        for (int t0 = s; t0 < e; t0 += TMAX) {
            const int tc = min(TMAX, e - t0);
            const int ntask = tc * NG;

            // phase A: 2-deep pipelined gather+softmax (sets A/B ping-pong)
            {
                DECLP(A) DECLP(B)
                LOADP(A, tid)                      // prologue
                for (int t = tid; t < ntask; t += 2*BT) {
                    LOADP(B, t + BT)               // in flight during COMPP(A)
                    COMPP(A)
                    if (t + 2*BT < ntask) LOADP(A, t + 2*BT)
                    COMPP(B)                       // clamped dup -> same-value write
                }
            }
            __syncthreads();

            // phase B: C[tc x 104] = X * W^T; wave wid (<7) owns nt = wid
            if (wid < 7) {
                const int mts = (tc + 15) >> 4;
                const int kg = (lane >> 4) * 8;
                const int r0 = wid*16 + (lane & 15);
                for (int mt = 0; mt < mts; ++mt) {
                    const int row_a = mt*16 + (lane & 15);
                    f32x4 a0 = {0.f,0.f,0.f,0.f}, b0 = {0.f,0.f,0.f,0.f}, c0 = {0.f,0.f,0.f,0.f};
                    #pragma unroll
                    for (int kt = 0; kt < 7; ++kt) {
                        const int k0 = kt*32 + kg;
                        short8 ah = *(const short8*)&x_hi[row_a][k0];
                        short8 al = *(const short8*)&x_lo[row_a][k0];
                        a0 = MFMA(ah, wh[kt], a0);
                        b0 = MFMA(ah, wl[kt], b0);
                        c0 = MFMA(al, wh[kt], c0);
                    }
                    f32x4 acc = a0 + b0 + c0;
                    if (r0 < LL) {
                        #pragma unroll
                        for (int j = 0; j < 4; ++j) {
                            int ni = mt*16 + (lane >> 4)*4 + j;
                            if (ni < tc) {
                                int n = order[t0 + ni];
                                float v = fmaxf(acc[j] + s_bm[r0], 0.f);
                                out_d[n*LL + r0] = v;
                                if (n == NN - 1) last_buf[d*LL + r0] = v;
                            }
                        }
                    }
                }
            }
            __syncthreads();  // x reuse + out_d visibility for next tile
        }
    }
#undef DECLP
#undef LOADP
#undef COMPP
}

// Cross-DAG softmax pool + final classifier. Single block.
__global__ __launch_bounds__(256) void final_pool_kernel(
    const float* __restrict__ last_buf,  // [DN][LL]
    const float* __restrict__ dag_w,     // [LL]
    const float* __restrict__ W_final,   // [CLS][LL]
    const float* __restrict__ b_final,   // [CLS]
    float* __restrict__ out)             // [CLS]
{
    __shared__ float s_pooled[LL];
    const int tid = threadIdx.x;

    if (tid < LL) {
        float dw = dag_w[tid];
        float m = -1e30f;
        #pragma unroll 8
        for (int dd = 0; dd < DN; ++dd)
            m = fmaxf(m, dw * last_buf[dd * LL + tid]);
        float den = 0.f, num = 0.f;
        #pragma unroll 8
        for (int dd = 0; dd < DN; ++dd) {
            float v = last_buf[dd * LL + tid];
            float e = __expf(dw * v - m);
            den += e;
            num = fmaf(e, v, num);
        }
        s_pooled[tid] = num / den;
    }
    __syncthreads();

    for (int c = tid; c < CLS; c += 256) {
        float acc = b_final[c];
        const float* wr = W_final + c * LL;
        #pragma unroll 8
        for (int l = 0; l < LL; ++l) acc = fmaf(wr[l], s_pooled[l], acc);
        out[c] = acc;
    }
}

extern "C" void kernel_launch(void* const* d_in, const int* in_sizes, int n_in,
                              void* d_out, int out_size, void* d_ws, size_t ws_size,
                              hipStream_t stream) {
    const float* atom     = (const float*)d_in[0];
    const int*   pred     = (const int*)  d_in[1];
    const float* W_single = (const float*)d_in[2];
    const float* b_single = (const float*)d_in[3];
    const float* W_merge  = (const float*)d_in[4];
    const float* b_merge  = (const float*)d_in[5];
    const float* attn_w   = (const float*)d_in[6];
    const float* dag_w    = (const float*)d_in[7];
    const float* W_final  = (const float*)d_in[8];
    const float* b_final  = (const float*)d_in[9];
    float* out = (float*)d_out;

    float* out_all  = (float*)d_ws;                       // [DN][NN][LL]
    float* last_buf = out_all + (size_t)DN * NN * LL;     // [DN][LL]

    dag_level_kernel<<<DN, BT, 0, stream>>>(atom, pred, W_single, b_single,
                                            W_merge, b_merge, attn_w,
                                            out_all, last_buf);
    final_pool_kernel<<<1, 256, 0, stream>>>(last_buf, dag_w, W_final, b_final, out);
}

// Round 10
// 387.813 us; speedup vs baseline: 1.0343x; 1.0343x over previous
//
#include <hip/hip_runtime.h>

#define DN  256   // DAGs
#define NN  1024  // nodes per DAG
#define PP  8     // max predecessors
#define LL  104   // feature dim
#define CLS 500   // classes
#define BT  512   // threads per block (8 waves)
#define TMAX 64   // node tile per level pass
#define KP  232   // padded K stride in bf16 elems (116 dwords % 32 = 20 -> 2-way max, free)
#define NG  26    // float4 feature groups (104/4)

typedef __attribute__((ext_vector_type(8))) short short8;
typedef __attribute__((ext_vector_type(4))) short short4v;
typedef __attribute__((ext_vector_type(4))) float f32x4;

#define MFMA(a, b, c) __builtin_amdgcn_mfma_f32_16x16x32_bf16((a), (b), (c), 0, 0, 0)

__device__ __forceinline__ void split_bf16(float x, unsigned short& h, unsigned short& l) {
    unsigned u = __float_as_uint(x);
    h = (unsigned short)(u >> 16);
    float hf = __uint_as_float(u & 0xFFFF0000u);
    l = (unsigned short)(__float_as_uint(x - hf) >> 16);
}

// softmax over preds + split-bf16 + LDS store for one (node, 4-feature) task
__device__ __forceinline__ void sm_store(int ni, int lg, const int pi[PP],
    const float4 pv[PP], float4 ft, const float* s_attn2,
    unsigned short (*xh)[KP], unsigned short (*xl)[KP])
{
    float4 aw = *(const float4*)&s_attn2[lg * 4];
    float awv[4] = {aw.x, aw.y, aw.z, aw.w};
    float ftv[4] = {ft.x, ft.y, ft.z, ft.w};
    unsigned short oh[8], ol[8];
    #pragma unroll
    for (int f = 0; f < 4; ++f) {
        float den = 0.f, num = 0.f;
        #pragma unroll
        for (int q = 0; q < PP; ++q) {
            float pvq = ((const float*)&pv[q])[f];
            float e2 = exp2f(awv[f] * pvq);     // shift-invariant; bounded values
            e2 = (pi[q] >= 0) ? e2 : 0.f;       // arithmetic mask
            den += e2;
            num = fmaf(e2, pvq, num);
        }
        float agg = __fdividef(num, den);
        split_bf16(agg,    oh[f],     ol[f]);
        split_bf16(ftv[f], oh[4 + f], ol[4 + f]);
    }
    short4v h0 = {(short)oh[0], (short)oh[1], (short)oh[2], (short)oh[3]};
    short4v l0 = {(short)ol[0], (short)ol[1], (short)ol[2], (short)ol[3]};
    short4v h1 = {(short)oh[4], (short)oh[5], (short)oh[6], (short)oh[7]};
    short4v l1 = {(short)ol[4], (short)ol[5], (short)ol[6], (short)ol[7]};
    *(short4v*)&xh[ni][lg*4]      = h0;
    *(short4v*)&xl[ni][lg*4]      = l0;
    *(short4v*)&xh[ni][LL + lg*4] = h1;
    *(short4v*)&xl[ni][LL + lg*4] = l1;
}

// One block per DAG, 8 waves. Level-scheduled split-bf16 MFMA GEMM per level.
// Chain cuts: pred_idx in LDS; next-tile round-1 gathers prefetched during
// phase B (fresh lvl==L rows re-gathered from L2 after the barrier).
__global__ __launch_bounds__(BT, 2) void dag_level_kernel(
    const float* __restrict__ atom,      // [DN][NN][LL]
    const int*   __restrict__ pred,      // [DN][NN][PP]
    const float* __restrict__ W_single,  // [LL][LL]
    const float* __restrict__ b_single,  // [LL]
    const float* __restrict__ W_merge,   // [LL][2*LL]
    const float* __restrict__ b_merge,   // [LL]
    const float* __restrict__ attn_w,    // [LL]
    float* __restrict__ out_all,         // ws: [DN][NN][LL]
    float* __restrict__ last_buf)        // ws: [DN][LL]
{
    __shared__ __align__(16) unsigned short x_hi[TMAX][KP];  // 29.7 KB
    __shared__ __align__(16) unsigned short x_lo[TMAX][KP];  // 29.7 KB
    __shared__ __align__(16) int pred_lds[NN][PP];           // 32 KB
    __shared__ int   lvl[NN];               // 4 KB
    __shared__ int   cnt[NN];               // 4 KB
    __shared__ unsigned short order[NN];    // 2 KB
    __shared__ __align__(16) float s_attn2[LL];   // attn_w * log2(e)
    __shared__ float s_bm[LL];
    __shared__ int   csum[64];
    __shared__ int   s_flag, s_maxlvl;

    const int d    = blockIdx.x;
    const int tid  = threadIdx.x;
    const int wid  = tid >> 6;
    const int lane = tid & 63;

    const float* atom_d = atom + (size_t)d * NN * LL;
    const int*   pred_d = pred + (size_t)d * NN * PP;
    float*       out_d  = out_all + (size_t)d * NN * LL;

    // ---- stage pred_idx into LDS (once) ----
    for (int idx = tid; idx < NN * PP / 4; idx += BT)
        ((int4*)pred_lds)[idx] = ((const int4*)pred_d)[idx];

    // ---- W_merge fragments -> registers. Wave w owns nt = min(w,6):
    // lane holds W[col = nt*16 + (lane&15)][k = kt*32 + (lane>>4)*8 + j].
    short8 wh[7], wl[7];
    {
        const int r = min(wid, 6)*16 + (lane & 15);
        #pragma unroll
        for (int kt = 0; kt < 7; ++kt) {
            const int k0 = kt*32 + (lane >> 4)*8;
            short8 hh, lo8;
            #pragma unroll
            for (int j = 0; j < 8; ++j) {
                float v = (r < LL && (k0 + j) < 2*LL) ? W_merge[r*2*LL + k0 + j] : 0.f;
                unsigned short a, b;
                split_bf16(v, a, b);
                hh[j] = (short)a; lo8[j] = (short)b;
            }
            wh[kt] = hh; wl[kt] = lo8;
        }
    }

    // ---- init: zero x pad cols, stage attn/bias, init flags ----
    for (int idx = tid; idx < TMAX * (KP - 2*LL); idx += BT) {
        int rr = idx / (KP - 2*LL), cc = 2*LL + (idx - rr*(KP - 2*LL));
        x_hi[rr][cc] = 0; x_lo[rr][cc] = 0;
    }
    if (tid < LL) { s_attn2[tid] = attn_w[tid] * 1.44269504f; s_bm[tid] = b_merge[tid]; }
    if (tid == 0) { s_flag = 0; s_maxlvl = 0; }
    lvl[tid] = 0; lvl[tid + BT] = 0;
    __syncthreads();   // pred_lds + lvl init visible

    // ---- 1. level relaxation: 2 nodes/thread, DOUBLE monotone sweep/barrier ----
    {
        int mypA[PP], mypB[PP];
        #pragma unroll
        for (int q = 0; q < PP; ++q) { mypA[q] = pred_lds[tid][q]; mypB[q] = pred_lds[tid + BT][q]; }
        for (int it = 1; it <= NN; ++it) {
            bool ch = false;
            #pragma unroll
            for (int rep = 0; rep < 2; ++rep) {
                int mxA = -1, mxB = -1;
                #pragma unroll
                for (int q = 0; q < PP; ++q) {
                    if (mypA[q] >= 0) mxA = max(mxA, lvl[mypA[q]]);
                    if (mypB[q] >= 0) mxB = max(mxB, lvl[mypB[q]]);
                }
                if (mxA + 1 != lvl[tid])      { lvl[tid]      = mxA + 1; ch = true; }
                if (mxB + 1 != lvl[tid + BT]) { lvl[tid + BT] = mxB + 1; ch = true; }
            }
            if (ch) s_flag = it;
            __syncthreads();
            int f = s_flag;
            __syncthreads();
            if (f != it) break;   // full quiescent double-sweep -> fixpoint
        }
        atomicMax(&s_maxlvl, max(lvl[tid], lvl[tid + BT]));
    }

    // ---- 2. counting sort by level ----
    cnt[tid] = 0; cnt[tid + BT] = 0;
    __syncthreads();
    atomicAdd(&cnt[lvl[tid]], 1);
    atomicAdd(&cnt[lvl[tid + BT]], 1);
    __syncthreads();
    if (tid < 64) { int s = 0; for (int i = 0; i < 16; ++i) s += cnt[tid*16 + i]; csum[tid] = s; }
    __syncthreads();
    if (tid == 0) { int run = 0; for (int t = 0; t < 64; ++t) { int c = csum[t]; csum[t] = run; run += c; } }
    __syncthreads();
    if (tid < 64) {
        int run = csum[tid];
        for (int i = 0; i < 16; ++i) { int c = cnt[tid*16 + i]; cnt[tid*16 + i] = run; run += c; }
    }
    __syncthreads();
    {
        int pos = atomicAdd(&cnt[lvl[tid]], 1);      order[pos] = (unsigned short)tid;
        pos     = atomicAdd(&cnt[lvl[tid + BT]], 1); order[pos] = (unsigned short)(tid + BT);
    }
    __syncthreads();
    // level L occupies [L==0 ? 0 : cnt[L-1], cnt[L])

    // ---- 3. level-0 (root) nodes via W_single (level 0 = {node 0}) ----
    {
        int nroots = cnt[0];
        for (int task = tid; task < nroots * LL; task += BT) {
            int ni = task / LL, r = task - ni * LL;
            int n = order[ni];
            float acc = b_single[r];
            const float* feat = atom_d + n * LL;
            const float* wr = W_single + r * LL;
            #pragma unroll 8
            for (int l = 0; l < LL; ++l) acc = fmaf(wr[l], feat[l], acc);
            float v = fmaxf(acc, 0.f);
            out_d[n * LL + r] = v;
            if (n == NN - 1) last_buf[d * LL + r] = v;
        }
    }
    __syncthreads();

    const int maxlvl = s_maxlvl;

    // ---- prefetch state: round-1 task (tid) of the NEXT tile ----
    float4 pf_po[PP];
    float4 pf_ft = {0.f, 0.f, 0.f, 0.f};
    int    pf_fresh = 0;

    // Issue gathers for tile [NT0, NT0+NTC) while level LCUR is being written.
    // Rows with lvl==LCUR are redirected to row 0 and re-gathered post-barrier.
#define PREFETCH(NT0, NTC, LCUR) do {                                          \
        pf_fresh = 0;                                                          \
        if (tid < (NTC) * NG) {                                                \
            int ni_ = tid / NG, lg_ = tid - ni_ * NG;                          \
            int n_ = order[(NT0) + ni_];                                       \
            pf_ft = *(const float4*)&atom_d[n_ * LL + lg_ * 4];                \
            _Pragma("unroll")                                                  \
            for (int q_ = 0; q_ < PP; ++q_) {                                  \
                int pi_ = pred_lds[n_][q_];                                    \
                bool fr_ = (pi_ >= 0) && (lvl[pi_] == (LCUR));                 \
                int row_ = fr_ ? 0 : max(pi_, 0);                              \
                pf_fresh |= (fr_ ? 1 : 0) << q_;                               \
                pf_po[q_] = *(const float4*)&out_d[row_ * LL + lg_ * 4];       \
            }                                                                  \
        }                                                                      \
    } while (0)

    // prologue: first tile of level 1 (preds are node 0, just written -> L2)
    if (maxlvl >= 1) {
        int s1 = cnt[0];
        int ntc0 = min(TMAX, cnt[1] - s1);
        PREFETCH(s1, ntc0, 0);
    }

    // ---- 4. main level loop ----
    for (int L = 1; L <= maxlvl; ++L) {
        const int s = cnt[L - 1], e = cnt[L];
        for (int t0 = s; t0 < e; t0 += TMAX) {
            const int tc = min(TMAX, e - t0);
            const int ntask = tc * NG;

            // ---------- phase A ----------
            // round 1: prefetched; re-gather only fresh rows (L2-hot)
            if (tid < ntask) {
                int ni = tid / NG, lg = tid - ni * NG;
                int n = order[t0 + ni];
                int pi[PP];
                #pragma unroll
                for (int q = 0; q < PP; ++q) pi[q] = pred_lds[n][q];
                float4 rg[PP];
                #pragma unroll
                for (int q = 0; q < PP; ++q) {
                    int row = ((pf_fresh >> q) & 1) ? pi[q] : 0;
                    rg[q] = *(const float4*)&out_d[row * LL + lg * 4];
                }
                float4 pv[PP];
                #pragma unroll
                for (int q = 0; q < PP; ++q)
                    pv[q] = ((pf_fresh >> q) & 1) ? rg[q] : pf_po[q];
                sm_store(ni, lg, pi, pv, pf_ft, s_attn2, x_hi, x_lo);
            }
            // rounds 2+ (big levels only): plain branchless path
            for (int task = tid + BT; task < ntask; task += BT) {
                int ni = task / NG, lg = task - ni * NG;
                int n = order[t0 + ni];
                int pi[PP];
                #pragma unroll
                for (int q = 0; q < PP; ++q) pi[q] = pred_lds[n][q];
                float4 pv[PP];
                #pragma unroll
                for (int q = 0; q < PP; ++q) {
                    int row = max(pi[q], 0);
                    pv[q] = *(const float4*)&out_d[row * LL + lg * 4];
                }
                float4 ft = *(const float4*)&atom_d[n * LL + lg * 4];
                sm_store(ni, lg, pi, pv, ft, s_attn2, x_hi, x_lo);
            }
            __syncthreads();

            // ---------- phase B ----------
            // issue next tile's prefetch first (hidden under MFMA/stores)
            {
                int nt0 = 0, ntc = 0;
                if (t0 + TMAX < e)        { nt0 = t0 + TMAX; ntc = min(TMAX, e - nt0); }
                else if (L + 1 <= maxlvl) { nt0 = e;         ntc = min(TMAX, cnt[L + 1] - e); }
                PREFETCH(nt0, ntc, L);
            }

            if (wid < 7) {
                const int mts = (tc + 15) >> 4;
                const int kg = (lane >> 4) * 8;
                const int r0 = wid*16 + (lane & 15);
                for (int mt = 0; mt < mts; ++mt) {
                    const int row_a = mt*16 + (lane & 15);
                    f32x4 a0 = {0.f,0.f,0.f,0.f}, b0 = {0.f,0.f,0.f,0.f}, c0 = {0.f,0.f,0.f,0.f};
                    #pragma unroll
                    for (int kt = 0; kt < 7; ++kt) {
                        const int k0 = kt*32 + kg;
                        short8 ah = *(const short8*)&x_hi[row_a][k0];
                        short8 al = *(const short8*)&x_lo[row_a][k0];
                        a0 = MFMA(ah, wh[kt], a0);
                        b0 = MFMA(ah, wl[kt], b0);
                        c0 = MFMA(al, wh[kt], c0);
                    }
                    f32x4 acc = a0 + b0 + c0;
                    if (r0 < LL) {
                        #pragma unroll
                        for (int j = 0; j < 4; ++j) {
                            int ni = mt*16 + (lane >> 4)*4 + j;
                            if (ni < tc) {
                                int n = order[t0 + ni];
                                float v = fmaxf(acc[j] + s_bm[r0], 0.f);
                                out_d[n*LL + r0] = v;
                                if (n == NN - 1) last_buf[d*LL + r0] = v;
                            }
                        }
                    }
                }
            }
            __syncthreads();  // x reuse + out_d visibility for next tile
        }
    }
#undef PREFETCH
}

// Cross-DAG softmax pool + final classifier. Single block.
__global__ __launch_bounds__(256) void final_pool_kernel(
    const float* __restrict__ last_buf,  // [DN][LL]
    const float* __restrict__ dag_w,     // [LL]
    const float* __restrict__ W_final,   // [CLS][LL]
    const float* __restrict__ b_final,   // [CLS]
    float* __restrict__ out)             // [CLS]
{
    __shared__ float s_pooled[LL];
    const int tid = threadIdx.x;

    if (tid < LL) {
        float dw = dag_w[tid];
        float m = -1e30f;
        #pragma unroll 8
        for (int dd = 0; dd < DN; ++dd)
            m = fmaxf(m, dw * last_buf[dd * LL + tid]);
        float den = 0.f, num = 0.f;
        #pragma unroll 8
        for (int dd = 0; dd < DN; ++dd) {
            float v = last_buf[dd * LL + tid];
            float e = __expf(dw * v - m);
            den += e;
            num = fmaf(e, v, num);
        }
        s_pooled[tid] = num / den;
    }
    __syncthreads();

    for (int c = tid; c < CLS; c += 256) {
        float acc = b_final[c];
        const float* wr = W_final + c * LL;
        #pragma unroll 8
        for (int l = 0; l < LL; ++l) acc = fmaf(wr[l], s_pooled[l], acc);
        out[c] = acc;
    }
}

extern "C" void kernel_launch(void* const* d_in, const int* in_sizes, int n_in,
                              void* d_out, int out_size, void* d_ws, size_t ws_size,
                              hipStream_t stream) {
    const float* atom     = (const float*)d_in[0];
    const int*   pred     = (const int*)  d_in[1];
    const float* W_single = (const float*)d_in[2];
    const float* b_single = (const float*)d_in[3];
    const float* W_merge  = (const float*)d_in[4];
    const float* b_merge  = (const float*)d_in[5];
    const float* attn_w   = (const float*)d_in[6];
    const float* dag_w    = (const float*)d_in[7];
    const float* W_final  = (const float*)d_in[8];
    const float* b_final  = (const float*)d_in[9];
    float* out = (float*)d_out;

    float* out_all  = (float*)d_ws;                       // [DN][NN][LL]
    float* last_buf = out_all + (size_t)DN * NN * LL;     // [DN][LL]

    dag_level_kernel<<<DN, BT, 0, stream>>>(atom, pred, W_single, b_single,
                                            W_merge, b_merge, attn_w,
                                            out_all, last_buf);
    final_pool_kernel<<<1, 256, 0, stream>>>(last_buf, dag_w, W_final, b_final, out);
}

// Round 11
// 373.640 us; speedup vs baseline: 1.0735x; 1.0379x over previous
//
#include <hip/hip_runtime.h>

#define DN  256   // DAGs
#define NN  1024  // nodes per DAG
#define PP  8     // max predecessors
#define LL  104   // feature dim
#define CLS 500   // classes
#define BT  512   // threads per block (8 waves)
#define TMAX 64   // node tile per level pass
#define KP  232   // padded K stride in bf16 elems
#define NG  26    // float4 feature groups (104/4)

typedef __attribute__((ext_vector_type(8))) short short8;
typedef __attribute__((ext_vector_type(4))) short short4v;
typedef __attribute__((ext_vector_type(4))) float f32x4;

#define MFMA(a, b, c) __builtin_amdgcn_mfma_f32_16x16x32_bf16((a), (b), (c), 0, 0, 0)

__device__ __forceinline__ void split_bf16(float x, unsigned short& h, unsigned short& l) {
    unsigned u = __float_as_uint(x);
    h = (unsigned short)(u >> 16);
    float hf = __uint_as_float(u & 0xFFFF0000u);
    l = (unsigned short)(__float_as_uint(x - hf) >> 16);
}

// softmax over preds + split-bf16 + LDS store for one (node, 4-feature) task
__device__ __forceinline__ void sm_store(int ni, int lg, const int pi[PP],
    const float4 pv[PP], float4 ft, const float* s_attn2,
    unsigned short (*xh)[KP], unsigned short (*xl)[KP])
{
    float4 aw = *(const float4*)&s_attn2[lg * 4];
    float awv[4] = {aw.x, aw.y, aw.z, aw.w};
    float ftv[4] = {ft.x, ft.y, ft.z, ft.w};
    unsigned short oh[8], ol[8];
    #pragma unroll
    for (int f = 0; f < 4; ++f) {
        float den = 0.f, num = 0.f;
        #pragma unroll
        for (int q = 0; q < PP; ++q) {
            float pvq = ((const float*)&pv[q])[f];
            float e2 = exp2f(awv[f] * pvq);     // shift-invariant; bounded values
            e2 = (pi[q] >= 0) ? e2 : 0.f;       // arithmetic mask
            den += e2;
            num = fmaf(e2, pvq, num);
        }
        float agg = __fdividef(num, den);
        split_bf16(agg,    oh[f],     ol[f]);
        split_bf16(ftv[f], oh[4 + f], ol[4 + f]);
    }
    short4v h0 = {(short)oh[0], (short)oh[1], (short)oh[2], (short)oh[3]};
    short4v l0 = {(short)ol[0], (short)ol[1], (short)ol[2], (short)ol[3]};
    short4v h1 = {(short)oh[4], (short)oh[5], (short)oh[6], (short)oh[7]};
    short4v l1 = {(short)ol[4], (short)ol[5], (short)ol[6], (short)ol[7]};
    *(short4v*)&xh[ni][lg*4]      = h0;
    *(short4v*)&xl[ni][lg*4]      = l0;
    *(short4v*)&xh[ni][LL + lg*4] = h1;
    *(short4v*)&xl[ni][LL + lg*4] = l1;
}

// One block per DAG, 8 waves. Level-scheduled split-bf16 MFMA GEMM per level.
// Per-tile chain has NO dependent global loads: non-fresh preds prefetched to
// registers during previous phase B; fresh preds (written in the previous
// tile) are mirrored in LDS (out_lds) and read there.
__global__ __launch_bounds__(BT, 2) void dag_level_kernel(
    const float* __restrict__ atom,      // [DN][NN][LL]
    const int*   __restrict__ pred,      // [DN][NN][PP]
    const float* __restrict__ W_single,  // [LL][LL]
    const float* __restrict__ b_single,  // [LL]
    const float* __restrict__ W_merge,   // [LL][2*LL]
    const float* __restrict__ b_merge,   // [LL]
    const float* __restrict__ attn_w,    // [LL]
    float* __restrict__ out_all,         // ws: [DN][NN][LL]
    float* __restrict__ last_buf)        // ws: [DN][LL]
{
    __shared__ __align__(16) unsigned short x_hi[TMAX][KP];  // 29.7 KB
    __shared__ __align__(16) unsigned short x_lo[TMAX][KP];  // 29.7 KB
    __shared__ __align__(16) int pred_lds[NN][PP];           // 32 KB
    __shared__ __align__(16) float out_lds[TMAX][LL];        // 26.6 KB prev-tile outputs
    __shared__ int   lvl[NN];                                // 4 KB
    __shared__ int   cnt[NN];                                // 4 KB
    __shared__ unsigned short order[NN];                     // 2 KB
    __shared__ unsigned short pos_lds[NN];                   // 2 KB node -> order position
    __shared__ __align__(16) float s_attn2[LL];              // attn_w * log2(e)
    __shared__ float s_bm[LL];
    __shared__ int   csum[64];
    __shared__ int   s_flag, s_maxlvl;

    const int d    = blockIdx.x;
    const int tid  = threadIdx.x;
    const int wid  = tid >> 6;
    const int lane = tid & 63;

    const float* atom_d = atom + (size_t)d * NN * LL;
    const int*   pred_d = pred + (size_t)d * NN * PP;
    float*       out_d  = out_all + (size_t)d * NN * LL;

    // ---- stage pred_idx into LDS (once) ----
    for (int idx = tid; idx < NN * PP / 4; idx += BT)
        ((int4*)pred_lds)[idx] = ((const int4*)pred_d)[idx];

    // ---- W_merge fragments -> registers. Wave w owns nt = min(w,6) ----
    short8 wh[7], wl[7];
    {
        const int r = min(wid, 6)*16 + (lane & 15);
        #pragma unroll
        for (int kt = 0; kt < 7; ++kt) {
            const int k0 = kt*32 + (lane >> 4)*8;
            short8 hh, lo8;
            #pragma unroll
            for (int j = 0; j < 8; ++j) {
                float v = (r < LL && (k0 + j) < 2*LL) ? W_merge[r*2*LL + k0 + j] : 0.f;
                unsigned short a, b;
                split_bf16(v, a, b);
                hh[j] = (short)a; lo8[j] = (short)b;
            }
            wh[kt] = hh; wl[kt] = lo8;
        }
    }

    // ---- init ----
    for (int idx = tid; idx < TMAX * (KP - 2*LL); idx += BT) {
        int rr = idx / (KP - 2*LL), cc = 2*LL + (idx - rr*(KP - 2*LL));
        x_hi[rr][cc] = 0; x_lo[rr][cc] = 0;
    }
    if (tid < LL) { s_attn2[tid] = attn_w[tid] * 1.44269504f; s_bm[tid] = b_merge[tid]; }
    if (tid == 0) { s_flag = 0; s_maxlvl = 0; }
    lvl[tid] = 0; lvl[tid + BT] = 0;
    __syncthreads();

    // ---- 1. level relaxation: 2 nodes/thread, double monotone sweep ----
    {
        int mypA[PP], mypB[PP];
        #pragma unroll
        for (int q = 0; q < PP; ++q) { mypA[q] = pred_lds[tid][q]; mypB[q] = pred_lds[tid + BT][q]; }
        for (int it = 1; it <= NN; ++it) {
            bool ch = false;
            #pragma unroll
            for (int rep = 0; rep < 2; ++rep) {
                int mxA = -1, mxB = -1;
                #pragma unroll
                for (int q = 0; q < PP; ++q) {
                    if (mypA[q] >= 0) mxA = max(mxA, lvl[mypA[q]]);
                    if (mypB[q] >= 0) mxB = max(mxB, lvl[mypB[q]]);
                }
                if (mxA + 1 != lvl[tid])      { lvl[tid]      = mxA + 1; ch = true; }
                if (mxB + 1 != lvl[tid + BT]) { lvl[tid + BT] = mxB + 1; ch = true; }
            }
            if (ch) s_flag = it;
            __syncthreads();
            int f = s_flag;
            __syncthreads();
            if (f != it) break;
        }
        atomicMax(&s_maxlvl, max(lvl[tid], lvl[tid + BT]));
    }

    // ---- 2. counting sort by level (+ pos table) ----
    cnt[tid] = 0; cnt[tid + BT] = 0;
    __syncthreads();
    atomicAdd(&cnt[lvl[tid]], 1);
    atomicAdd(&cnt[lvl[tid + BT]], 1);
    __syncthreads();
    if (tid < 64) { int s = 0; for (int i = 0; i < 16; ++i) s += cnt[tid*16 + i]; csum[tid] = s; }
    __syncthreads();
    if (tid == 0) { int run = 0; for (int t = 0; t < 64; ++t) { int c = csum[t]; csum[t] = run; run += c; } }
    __syncthreads();
    if (tid < 64) {
        int run = csum[tid];
        for (int i = 0; i < 16; ++i) { int c = cnt[tid*16 + i]; cnt[tid*16 + i] = run; run += c; }
    }
    __syncthreads();
    {
        int pos = atomicAdd(&cnt[lvl[tid]], 1);
        order[pos] = (unsigned short)tid;      pos_lds[tid] = (unsigned short)pos;
        pos = atomicAdd(&cnt[lvl[tid + BT]], 1);
        order[pos] = (unsigned short)(tid + BT); pos_lds[tid + BT] = (unsigned short)pos;
    }
    __syncthreads();
    // level L occupies [L==0 ? 0 : cnt[L-1], cnt[L])

    // ---- 3. level-0 (root) nodes via W_single; mirror into out_lds ----
    {
        int nroots = cnt[0];
        for (int task = tid; task < nroots * LL; task += BT) {
            int ni = task / LL, r = task - ni * LL;
            int n = order[ni];
            float acc = b_single[r];
            const float* feat = atom_d + n * LL;
            const float* wr = W_single + r * LL;
            #pragma unroll 8
            for (int l = 0; l < LL; ++l) acc = fmaf(wr[l], feat[l], acc);
            float v = fmaxf(acc, 0.f);
            out_d[n * LL + r] = v;
            if (ni < TMAX) out_lds[ni][r] = v;
            if (n == NN - 1) last_buf[d * LL + r] = v;
        }
    }
    __syncthreads();

    const int maxlvl = s_maxlvl;

    // ---- prefetch state for round-1 task (tid) of the NEXT tile ----
    float4 pf_po[PP];                 // non-fresh pred rows (global, final)
    float4 pf_ft = {0.f, 0.f, 0.f, 0.f};
    int    pf_fresh = 0;              // bit q: pred is in tile (CT0,CTC) -> out_lds

    // Issue gathers for next tile [NT0,NT0+NTC) while tile (CT0,CTC) is written.
#define PREFETCH(NT0, NTC, CT0, CTC) do {                                      \
        pf_fresh = 0;                                                          \
        if (tid < (NTC) * NG) {                                                \
            int ni_ = tid / NG, lg_ = tid - ni_ * NG;                          \
            int n_ = order[(NT0) + ni_];                                       \
            pf_ft = *(const float4*)&atom_d[n_ * LL + lg_ * 4];                \
            _Pragma("unroll")                                                  \
            for (int q_ = 0; q_ < PP; ++q_) {                                  \
                int pi_ = pred_lds[n_][q_];                                    \
                unsigned rel_ = (unsigned)((int)pos_lds[max(pi_, 0)] - (CT0)); \
                bool il_ = (pi_ >= 0) && (rel_ < (unsigned)(CTC));             \
                pf_fresh |= (il_ ? 1 : 0) << q_;                               \
                int row_ = il_ ? 0 : max(pi_, 0);                              \
                pf_po[q_] = *(const float4*)&out_d[row_ * LL + lg_ * 4];       \
            }                                                                  \
        }                                                                      \
    } while (0)

    int pt0 = 0, ptc = cnt[0];   // "previous tile" = level-0 tile

    // prologue: first tile of level 1
    if (maxlvl >= 1) {
        int s1 = cnt[0];
        PREFETCH(s1, min(TMAX, cnt[1] - s1), 0, ptc);
    }

    // ---- 4. main level loop ----
    for (int L = 1; L <= maxlvl; ++L) {
        const int s = cnt[L - 1], e = cnt[L];
        for (int t0 = s; t0 < e; t0 += TMAX) {
            const int tc = min(TMAX, e - t0);
            const int ntask = tc * NG;

            // ---------- phase A ----------
            // round 1: no dependent global loads (pf regs + out_lds)
            if (tid < ntask) {
                int ni = tid / NG, lg = tid - ni * NG;
                int n = order[t0 + ni];
                int pi[PP];
                #pragma unroll
                for (int q = 0; q < PP; ++q) pi[q] = pred_lds[n][q];
                float4 pv[PP];
                #pragma unroll
                for (int q = 0; q < PP; ++q) {
                    bool il = (pf_fresh >> q) & 1;
                    int slot = il ? ((int)pos_lds[max(pi[q], 0)] - pt0) : 0;
                    float4 lv = *(const float4*)&out_lds[slot][lg * 4];
                    pv[q] = il ? lv : pf_po[q];
                }
                sm_store(ni, lg, pi, pv, pf_ft, s_attn2, x_hi, x_lo);
            }
            // rounds 2+ (tc > 19 only): global path with LDS override for fresh
            for (int task = tid + BT; task < ntask; task += BT) {
                int ni = task / NG, lg = task - ni * NG;
                int n = order[t0 + ni];
                int pi[PP]; int ilm = 0; int slot[PP];
                #pragma unroll
                for (int q = 0; q < PP; ++q) {
                    pi[q] = pred_lds[n][q];
                    int rel = (int)pos_lds[max(pi[q], 0)] - pt0;
                    bool il = (pi[q] >= 0) && ((unsigned)rel < (unsigned)ptc);
                    ilm |= (il ? 1 : 0) << q;
                    slot[q] = il ? rel : 0;
                }
                float4 gv[PP];
                #pragma unroll
                for (int q = 0; q < PP; ++q) {
                    int row = ((ilm >> q) & 1) ? 0 : max(pi[q], 0);
                    gv[q] = *(const float4*)&out_d[row * LL + lg * 4];
                }
                float4 pv[PP];
                #pragma unroll
                for (int q = 0; q < PP; ++q) {
                    float4 lv = *(const float4*)&out_lds[slot[q]][lg * 4];
                    pv[q] = ((ilm >> q) & 1) ? lv : gv[q];
                }
                float4 ft = *(const float4*)&atom_d[n * LL + lg * 4];
                sm_store(ni, lg, pi, pv, ft, s_attn2, x_hi, x_lo);
            }
            __syncthreads();

            // ---------- phase B ----------
            // issue next tile's prefetch first (hidden under MFMA/stores)
            {
                int nt0 = 0, ntc = 0;
                if (t0 + TMAX < e)        { nt0 = t0 + TMAX; ntc = min(TMAX, e - nt0); }
                else if (L + 1 <= maxlvl) { nt0 = e;         ntc = min(TMAX, cnt[L + 1] - e); }
                PREFETCH(nt0, ntc, t0, tc);
            }

            if (wid < 7) {
                const int mts = (tc + 15) >> 4;
                const int kg = (lane >> 4) * 8;
                const int r0 = wid*16 + (lane & 15);
                for (int mt = 0; mt < mts; ++mt) {
                    const int row_a = mt*16 + (lane & 15);
                    f32x4 a0 = {0.f,0.f,0.f,0.f}, b0 = {0.f,0.f,0.f,0.f}, c0 = {0.f,0.f,0.f,0.f};
                    #pragma unroll
                    for (int kt = 0; kt < 7; ++kt) {
                        const int k0 = kt*32 + kg;
                        short8 ah = *(const short8*)&x_hi[row_a][k0];
                        short8 al = *(const short8*)&x_lo[row_a][k0];
                        a0 = MFMA(ah, wh[kt], a0);
                        b0 = MFMA(ah, wl[kt], b0);
                        c0 = MFMA(al, wh[kt], c0);
                    }
                    f32x4 acc = a0 + b0 + c0;
                    if (r0 < LL) {
                        #pragma unroll
                        for (int j = 0; j < 4; ++j) {
                            int ni = mt*16 + (lane >> 4)*4 + j;
                            if (ni < tc) {
                                int n = order[t0 + ni];
                                float v = fmaxf(acc[j] + s_bm[r0], 0.f);
                                out_d[n*LL + r0] = v;
                                out_lds[ni][r0] = v;           // LDS mirror
                                if (n == NN - 1) last_buf[d*LL + r0] = v;
                            }
                        }
                    }
                }
            }
            __syncthreads();  // x/out_lds reuse + visibility for next tile
            pt0 = t0; ptc = tc;
        }
    }
#undef PREFETCH
}

// Cross-DAG softmax pool + final classifier. Single block.
__global__ __launch_bounds__(256) void final_pool_kernel(
    const float* __restrict__ last_buf,  // [DN][LL]
    const float* __restrict__ dag_w,     // [LL]
    const float* __restrict__ W_final,   // [CLS][LL]
    const float* __restrict__ b_final,   // [CLS]
    float* __restrict__ out)             // [CLS]
{
    __shared__ float s_pooled[LL];
    const int tid = threadIdx.x;

    if (tid < LL) {
        float dw = dag_w[tid];
        float m = -1e30f;
        #pragma unroll 8
        for (int dd = 0; dd < DN; ++dd)
            m = fmaxf(m, dw * last_buf[dd * LL + tid]);
        float den = 0.f, num = 0.f;
        #pragma unroll 8
        for (int dd = 0; dd < DN; ++dd) {
            float v = last_buf[dd * LL + tid];
            float e = __expf(dw * v - m);
            den += e;
            num = fmaf(e, v, num);
        }
        s_pooled[tid] = num / den;
    }
    __syncthreads();

    for (int c = tid; c < CLS; c += 256) {
        float acc = b_final[c];
        const float* wr = W_final + c * LL;
        #pragma unroll 8
        for (int l = 0; l < LL; ++l) acc = fmaf(wr[l], s_pooled[l], acc);
        out[c] = acc;
    }
}

extern "C" void kernel_launch(void* const* d_in, const int* in_sizes, int n_in,
                              void* d_out, int out_size, void* d_ws, size_t ws_size,
                              hipStream_t stream) {
    const float* atom     = (const float*)d_in[0];
    const int*   pred     = (const int*)  d_in[1];
    const float* W_single = (const float*)d_in[2];
    const float* b_single = (const float*)d_in[3];
    const float* W_merge  = (const float*)d_in[4];
    const float* b_merge  = (const float*)d_in[5];
    const float* attn_w   = (const float*)d_in[6];
    const float* dag_w    = (const float*)d_in[7];
    const float* W_final  = (const float*)d_in[8];
    const float* b_final  = (const float*)d_in[9];
    float* out = (float*)d_out;

    float* out_all  = (float*)d_ws;                       // [DN][NN][LL]
    float* last_buf = out_all + (size_t)DN * NN * LL;     // [DN][LL]

    dag_level_kernel<<<DN, BT, 0, stream>>>(atom, pred, W_single, b_single,
                                            W_merge, b_merge, attn_w,
                                            out_all, last_buf);
    final_pool_kernel<<<1, 256, 0, stream>>>(last_buf, dag_w, W_final, b_final, out);
}